// Round 10
// baseline (542.994 us; speedup 1.0000x reference)
//
#include <hip/hip_runtime.h>
#include <hip/hip_fp16.h>
#include <cstddef>

// ---------------------------------------------------------------------------
// CrystalGNN (SchNet-style). R10: half-wave-packed conv edge loop.
//   memset deg
//   k_pre     : hist deg[dst]++  +  gstart  +  x=emb[ids]  +  hA=x@W1_0+b1_0
//   scan a/b/c -> off[N+1], cursor[N]
//   k_scatter : dst-sorted SoA payload srcs[]=src*64, ab[]={A,B},
//               A=exp(-1.125 d^2), B=exp(1.5 d); RBF_r=A*B^r*C_r (C_r folded
//               into filter weights) -> conv hot loop transcendental-free
//   per layer : k_conv — 2 edges/wave-iter: lanes 0-31 even edges, 32-63 odd,
//               each lane owns a FEATURE PAIR (half2 gather, paired-f32
//               Horner -> v_pk_fma); 8 edges in flight. Epilogue shfl+W2.
//               then k_gemm (h_next = x@W1'+b1')
//   k_poolhead: per-graph mean + two 2-layer MLP heads
// ---------------------------------------------------------------------------

// C_r = exp(-0.5 r^2), r = 0..9
#define RBF_C0 1.0f
#define RBF_C1 0.60653065971f
#define RBF_C2 0.13533528324f
#define RBF_C3 0.011108996538f
#define RBF_C4 3.3546262790e-4f
#define RBF_C5 3.7266531720e-6f
#define RBF_C6 1.5229979745e-8f
#define RBF_C7 2.2897348457e-11f
#define RBF_C8 1.2664165549e-14f
#define RBF_C9 2.5767043600e-18f

__device__ __forceinline__ float softplusf(float v) {
    return fmaxf(v, 0.0f) + log1pf(__expf(-fabsf(v)));
}

__device__ __forceinline__ float row_gemv(const float4* __restrict__ xr,
                                          const float w[64], float bj) {
    float a0 = bj, a1 = 0.f, a2 = 0.f, a3 = 0.f;
#pragma unroll
    for (int q = 0; q < 4; ++q) {
        float4 v0 = xr[4 * q + 0], v1 = xr[4 * q + 1];
        float4 v2 = xr[4 * q + 2], v3 = xr[4 * q + 3];
        a0 = fmaf(v0.x, w[16 * q + 0], a0);  a0 = fmaf(v0.y, w[16 * q + 1], a0);
        a0 = fmaf(v0.z, w[16 * q + 2], a0);  a0 = fmaf(v0.w, w[16 * q + 3], a0);
        a1 = fmaf(v1.x, w[16 * q + 4], a1);  a1 = fmaf(v1.y, w[16 * q + 5], a1);
        a1 = fmaf(v1.z, w[16 * q + 6], a1);  a1 = fmaf(v1.w, w[16 * q + 7], a1);
        a2 = fmaf(v2.x, w[16 * q + 8], a2);  a2 = fmaf(v2.y, w[16 * q + 9], a2);
        a2 = fmaf(v2.z, w[16 * q + 10], a2); a2 = fmaf(v2.w, w[16 * q + 11], a2);
        a3 = fmaf(v3.x, w[16 * q + 12], a3); a3 = fmaf(v3.y, w[16 * q + 13], a3);
        a3 = fmaf(v3.z, w[16 * q + 14], a3); a3 = fmaf(v3.w, w[16 * q + 15], a3);
    }
    return (a0 + a1) + (a2 + a3);
}

// ---------------- hist + gstart + embed + gemm0 ----------------
__global__ void k_pre(const int* __restrict__ dst, int* __restrict__ deg,
                      const int* __restrict__ batch, int* __restrict__ gstart,
                      const int* __restrict__ ids, const float* __restrict__ emb,
                      const float* __restrict__ W1, const float* __restrict__ b1,
                      float* __restrict__ x, __half* __restrict__ hA,
                      int n_edges, int n_nodes, int n_graphs) {
    int tid = blockIdx.x * blockDim.x + threadIdx.x;
    int nth = gridDim.x * blockDim.x;
    for (int e = tid; e < n_edges; e += nth) atomicAdd(&deg[dst[e]], 1);
    for (int n = tid; n < n_nodes; n += nth) {
        int b = batch[n];
        int prev = (n == 0) ? -1 : batch[n - 1];
        for (int g = prev + 1; g <= b; ++g) gstart[g] = n;
        if (n == n_nodes - 1)
            for (int g = b + 1; g <= n_graphs; ++g) gstart[g] = n_nodes;
    }
    int lane = threadIdx.x & 63;
    int gw = __builtin_amdgcn_readfirstlane(tid >> 6);
    int nw = nth >> 6;
    float w[64];
#pragma unroll
    for (int k = 0; k < 64; ++k) w[k] = W1[k * 64 + lane];
    float bj = b1[lane];
    for (int n = gw; n < n_nodes; n += nw) {
        int id = __builtin_amdgcn_readfirstlane(ids[n]);
        const float4* xr = (const float4*)(emb + id * 64);
        float v = row_gemv(xr, w, bj);
        x[n * 64 + lane] = emb[id * 64 + lane];
        hA[n * 64 + lane] = __float2half(v);
    }
}

// ---------------- scan ----------------
__global__ void k_scana(const int* __restrict__ deg, int* __restrict__ off_,
                        int* __restrict__ bsum, int n) {
    __shared__ int s[256];
    int i = blockIdx.x * 256 + threadIdx.x;
    int v = (i < n) ? deg[i] : 0;
    s[threadIdx.x] = v;
    __syncthreads();
    for (int off = 1; off < 256; off <<= 1) {
        int t = (threadIdx.x >= off) ? s[threadIdx.x - off] : 0;
        __syncthreads();
        s[threadIdx.x] += t;
        __syncthreads();
    }
    if (i < n) off_[i + 1] = s[threadIdx.x];
    if (threadIdx.x == 255) bsum[blockIdx.x] = s[255];
}

__global__ void k_scanb(int* __restrict__ bsum, int nb) {
    __shared__ int s[256];
    int v = ((int)threadIdx.x < nb) ? bsum[threadIdx.x] : 0;
    s[threadIdx.x] = v;
    __syncthreads();
    for (int off = 1; off < 256; off <<= 1) {
        int t = (threadIdx.x >= off) ? s[threadIdx.x - off] : 0;
        __syncthreads();
        s[threadIdx.x] += t;
        __syncthreads();
    }
    if ((int)threadIdx.x < nb) bsum[threadIdx.x] = s[threadIdx.x] - v;  // exclusive
}

__global__ void k_scanc(const int* __restrict__ deg, const int* __restrict__ bsum,
                        int* __restrict__ off_, int* __restrict__ cursor, int n) {
    int i = blockIdx.x * blockDim.x + threadIdx.x;
    if (i < n) {
        int incl = off_[i + 1] + bsum[i >> 8];
        off_[i + 1] = incl;
        cursor[i] = incl - deg[i];
    }
    if (i == 0) off_[0] = 0;
}

// ---------------- scatter: SoA payload srcs[]=src*64, ab[]={A,B} ------------
__global__ void k_scatter(const int* __restrict__ src, const int* __restrict__ dst,
                          const float* __restrict__ dist, int* __restrict__ cursor,
                          int* __restrict__ srcs, float2* __restrict__ ab, int n_edges) {
    int e = blockIdx.x * blockDim.x + threadIdx.x;
    if (e >= n_edges) return;
    int t = dst[e];
    int pos = atomicAdd(&cursor[t], 1);
    float d = dist[e];
    float A = __expf(-1.125f * d * d);
    float B = __expf(1.5f * d);
    srcs[pos] = src[e] << 6;
    ab[pos] = make_float2(A, B);
}

// ---------------- gemm: h = x@W1_l + b1_l ----------------
__global__ __launch_bounds__(256, 4) void k_gemm(
        const float* __restrict__ X, const float* __restrict__ W,
        const float* __restrict__ bias, __half* __restrict__ Y, int n_nodes) {
    int lane = threadIdx.x & 63;
    int gw = __builtin_amdgcn_readfirstlane((blockIdx.x * blockDim.x + threadIdx.x) >> 6);
    int nw = (gridDim.x * blockDim.x) >> 6;
    float w[64];
#pragma unroll
    for (int k = 0; k < 64; ++k) w[k] = W[k * 64 + lane];
    float bj = bias[lane];
    for (int n = gw; n < n_nodes; n += nw) {
        const float4* xr = (const float4*)(X + n * 64);
        Y[n * 64 + lane] = __float2half(row_gemv(xr, w, bj));
    }
}

// ---------------- conv: half-wave packed edge loop ----------------
// Per wave-iter of the inner loop, lanes 0-31 process even edges, lanes 32-63
// odd edges; each lane owns features (2*fl, 2*fl+1) -> half2 gather (4 B/lane),
// Horner on paired floats (v_pk_fma-friendly). 8 edges in flight.
__device__ __forceinline__ void edge_acc(const float wpx[10], const float wpy[10],
                                         float bex, float bey,
                                         float A, float B, float2 g,
                                         float& ax, float& ay) {
    float Px = wpx[9], Py = wpy[9];
    Px = fmaf(B, Px, wpx[8]); Py = fmaf(B, Py, wpy[8]);
    Px = fmaf(B, Px, wpx[7]); Py = fmaf(B, Py, wpy[7]);
    Px = fmaf(B, Px, wpx[6]); Py = fmaf(B, Py, wpy[6]);
    Px = fmaf(B, Px, wpx[5]); Py = fmaf(B, Py, wpy[5]);
    Px = fmaf(B, Px, wpx[4]); Py = fmaf(B, Py, wpy[4]);
    Px = fmaf(B, Px, wpx[3]); Py = fmaf(B, Py, wpy[3]);
    Px = fmaf(B, Px, wpx[2]); Py = fmaf(B, Py, wpy[2]);
    Px = fmaf(B, Px, wpx[1]); Py = fmaf(B, Py, wpy[1]);
    Px = fmaf(B, Px, wpx[0]); Py = fmaf(B, Py, wpy[0]);
    float fx = fmaf(A, Px, bex);
    float fy = fmaf(A, Py, bey);
    ax = fmaf(g.x, fx, ax);
    ay = fmaf(g.y, fy, ay);
}

__global__ __launch_bounds__(256, 6) void k_conv(
        const int* __restrict__ srcs, const float2* __restrict__ ab,
        const int* __restrict__ off, const __half* __restrict__ h,
        const float* __restrict__ We, const float* __restrict__ be,
        const float* __restrict__ W2, const float* __restrict__ b2,
        float* __restrict__ x, int n_nodes) {
    int lane = threadIdx.x & 63;
    int half = lane >> 5;       // 0: even edges, 1: odd edges
    int fl   = lane & 31;       // feature-pair index -> features 2fl, 2fl+1
    int f0   = fl << 1;
    int gw = __builtin_amdgcn_readfirstlane((blockIdx.x * blockDim.x + threadIdx.x) >> 6);
    int nw = (gridDim.x * blockDim.x) >> 6;

    const float C[10] = {RBF_C0, RBF_C1, RBF_C2, RBF_C3, RBF_C4,
                         RBF_C5, RBF_C6, RBF_C7, RBF_C8, RBF_C9};
    float wpx[10], wpy[10];
#pragma unroll
    for (int r = 0; r < 10; ++r) {
        wpx[r] = We[r * 64 + f0] * C[r];
        wpy[r] = We[r * 64 + f0 + 1] * C[r];
    }
    float bex = be[f0], bey = be[f0 + 1];
    float b2j = b2[lane];

    for (int n = gw; n < n_nodes; n += nw) {
        int k0 = __builtin_amdgcn_readfirstlane(off[n]);
        int k1 = __builtin_amdgcn_readfirstlane(off[n + 1]);
        float ax = 0.f, ay = 0.f;
        int k = k0;
        // 8 edges per iter (4 per half-wave, 4 gathers in flight)
        for (; k + 8 <= k1; k += 8) {
            int e0 = k + half, e1 = k + 2 + half, e2 = k + 4 + half, e3 = k + 6 + half;
            int s0 = srcs[e0], s1 = srcs[e1], s2 = srcs[e2], s3 = srcs[e3];
            float2 ab0 = ab[e0], ab1 = ab[e1], ab2 = ab[e2], ab3 = ab[e3];
            float2 g0 = __half22float2(*(const __half2*)(h + s0 + f0));
            float2 g1 = __half22float2(*(const __half2*)(h + s1 + f0));
            float2 g2 = __half22float2(*(const __half2*)(h + s2 + f0));
            float2 g3 = __half22float2(*(const __half2*)(h + s3 + f0));
            edge_acc(wpx, wpy, bex, bey, ab0.x, ab0.y, g0, ax, ay);
            edge_acc(wpx, wpy, bex, bey, ab1.x, ab1.y, g1, ax, ay);
            edge_acc(wpx, wpy, bex, bey, ab2.x, ab2.y, g2, ax, ay);
            edge_acc(wpx, wpy, bex, bey, ab3.x, ab3.y, g3, ax, ay);
        }
        // 2 edges per iter
        for (; k + 2 <= k1; k += 2) {
            int e = k + half;
            int s = srcs[e];
            float2 abv = ab[e];
            float2 g = __half22float2(*(const __half2*)(h + s + f0));
            edge_acc(wpx, wpy, bex, bey, abv.x, abv.y, g, ax, ay);
        }
        // odd tail edge: processed by half 0 only
        if (k < k1 && half == 0) {
            int e = k1 - 1;
            int s = srcs[e];
            float2 abv = ab[e];
            float2 g = __half22float2(*(const __half2*)(h + s + f0));
            edge_acc(wpx, wpy, bex, bey, abv.x, abv.y, g, ax, ay);
        }
        // combine halves: lanes 0-31 get full acc for their feature pair
        ax += __shfl(ax, fl + 32);
        ay += __shfl(ay, fl + 32);
        // x_new = softplus(x + b2 + acc @ W2); acc_k lives on lane k>>1 (.x/.y)
        float o0 = b2j + x[n * 64 + lane];
        float o1 = 0.f, o2 = 0.f, o3 = 0.f;
#pragma unroll 4
        for (int kk = 0; kk < 16; ++kk) {
            float v0 = __shfl((kk & 1) ? ay : ax, kk >> 1);
            float v1 = __shfl(((kk + 16) & 1) ? ay : ax, (kk + 16) >> 1);
            float v2 = __shfl(((kk + 32) & 1) ? ay : ax, (kk + 32) >> 1);
            float v3 = __shfl(((kk + 48) & 1) ? ay : ax, (kk + 48) >> 1);
            o0 = fmaf(v0, W2[(kk)      * 64 + lane], o0);
            o1 = fmaf(v1, W2[(kk + 16) * 64 + lane], o1);
            o2 = fmaf(v2, W2[(kk + 32) * 64 + lane], o2);
            o3 = fmaf(v3, W2[(kk + 48) * 64 + lane], o3);
        }
        x[n * 64 + lane] = softplusf((o0 + o1) + (o2 + o3));
    }
}

// ---------------- fused pool + head: one block per graph ----------------
__global__ void k_poolhead(const float* __restrict__ x, const int* __restrict__ gstart,
                           const float* __restrict__ Ws, const float* __restrict__ bs,
                           const float* __restrict__ Wbg1, const float* __restrict__ bbg1,
                           const float* __restrict__ Wbg2, const float* __restrict__ bbg2,
                           const float* __restrict__ Weh1, const float* __restrict__ beh1,
                           const float* __restrict__ Weh2, const float* __restrict__ beh2,
                           float* __restrict__ out, int n_graphs) {
    __shared__ float red[256];
    __shared__ float c[64];
    __shared__ float h1[128];
    int g = blockIdx.x;
    int t = threadIdx.x, j = t & 63, part = t >> 6;
    int s0 = gstart[g], s1 = gstart[g + 1];
    float acc = 0.0f;
    for (int n = s0 + part; n < s1; n += 4) acc += x[n * 64 + j];
    red[t] = acc;
    __syncthreads();
    if (part == 0)
        c[j] = (red[j] + red[64 + j] + red[128 + j] + red[192 + j]) /
               fmaxf((float)(s1 - s0), 1.0f);
    __syncthreads();
    if (t < 128) {
        float av = bs[t];
#pragma unroll 8
        for (int k = 0; k < 64; ++k) av = fmaf(c[k], Ws[k * 128 + t], av);
        h1[t] = fmaxf(av, 0.0f);
    }
    __syncthreads();
    if (t < 128) {
        const float* W1p = (t < 64) ? Wbg1 : Weh1;
        const float* b1p = (t < 64) ? bbg1 : beh1;
        const float* W2p = (t < 64) ? Wbg2 : Weh2;
        float b2v = (t < 64) ? bbg2[0] : beh2[0];
        int ln = t & 63;
        float a2 = b1p[ln];
#pragma unroll 8
        for (int k = 0; k < 128; ++k) a2 = fmaf(h1[k], W1p[k * 64 + ln], a2);
        a2 = fmaxf(a2, 0.0f);
        float pr = a2 * W2p[ln];
#pragma unroll
        for (int off = 32; off > 0; off >>= 1) pr += __shfl_down(pr, off);
        if (ln == 0) out[(t < 64 ? 0 : n_graphs) + g] = pr + b2v;
    }
}

extern "C" void kernel_launch(void* const* d_in, const int* in_sizes, int n_in,
                              void* d_out, int out_size, void* d_ws, size_t ws_size,
                              hipStream_t stream) {
    const int*   x_ids = (const int*)d_in[0];
    const int*   eidx  = (const int*)d_in[1];
    const float* eattr = (const float*)d_in[2];
    const int*   batch = (const int*)d_in[3];
    const float* emb   = (const float*)d_in[4];
    const float* W1    = (const float*)d_in[5];
    const float* b1    = (const float*)d_in[6];
    const float* We    = (const float*)d_in[7];
    const float* be    = (const float*)d_in[8];
    const float* W2    = (const float*)d_in[9];
    const float* b2    = (const float*)d_in[10];
    const float* Ws_   = (const float*)d_in[11];
    const float* bs_   = (const float*)d_in[12];
    const float* Wbg1  = (const float*)d_in[13];
    const float* bbg1  = (const float*)d_in[14];
    const float* Wbg2  = (const float*)d_in[15];
    const float* bbg2  = (const float*)d_in[16];
    const float* Weh1  = (const float*)d_in[17];
    const float* beh1  = (const float*)d_in[18];
    const float* Weh2  = (const float*)d_in[19];
    const float* beh2  = (const float*)d_in[20];

    int n_nodes  = in_sizes[0];
    int n_edges  = in_sizes[2];
    int n_graphs = out_size / 2;
    const int* src = eidx;
    const int* dst = eidx + n_edges;

    char* p = (char*)d_ws;
    float* x     = (float*)p;   p += (size_t)n_nodes * 64 * sizeof(float);
    __half* hA   = (__half*)p;  p += (size_t)n_nodes * 64 * sizeof(__half);
    __half* hB   = (__half*)p;  p += (size_t)n_nodes * 64 * sizeof(__half);
    int* srcs    = (int*)p;     p += (size_t)n_edges * sizeof(int);
    float2* ab   = (float2*)p;  p += (size_t)n_edges * sizeof(float2);
    int* deg     = (int*)p;     p += (size_t)n_nodes * sizeof(int);
    int* off_    = (int*)p;     p += (size_t)(n_nodes + 1) * sizeof(int);
    int* cursor  = (int*)p;     p += (size_t)n_nodes * sizeof(int);
    int* bsum    = (int*)p;     p += 256 * sizeof(int);
    int* gstart  = (int*)p;     p += (size_t)(n_graphs + 1) * sizeof(int);
    float* out   = (float*)d_out;

    int nchunks = (n_nodes + 255) / 256;
    int nbE = (n_edges + 255) / 256;
    int nbN = (n_nodes + 255) / 256;

    hipMemsetAsync(deg, 0, (size_t)n_nodes * sizeof(int), stream);
    k_pre<<<nbE, 256, 0, stream>>>(dst, deg, batch, gstart, x_ids, emb, W1, b1,
                                   x, hA, n_edges, n_nodes, n_graphs);
    k_scana<<<nchunks, 256, 0, stream>>>(deg, off_, bsum, n_nodes);
    k_scanb<<<1, 256, 0, stream>>>(bsum, nchunks);
    k_scanc<<<nbN, 256, 0, stream>>>(deg, bsum, off_, cursor, n_nodes);
    k_scatter<<<nbE, 256, 0, stream>>>(src, dst, eattr, cursor, srcs, ab, n_edges);

    k_conv<<<4096, 256, 0, stream>>>(srcs, ab, off_, hA, We, be, W2, b2, x, n_nodes);
    k_gemm<<<1024, 256, 0, stream>>>(x, W1 + 4096, b1 + 64, hB, n_nodes);
    k_conv<<<4096, 256, 0, stream>>>(srcs, ab, off_, hB, We + 640, be + 64,
                                     W2 + 4096, b2 + 64, x, n_nodes);
    k_gemm<<<1024, 256, 0, stream>>>(x, W1 + 8192, b1 + 128, hA, n_nodes);
    k_conv<<<4096, 256, 0, stream>>>(srcs, ab, off_, hA, We + 1280, be + 128,
                                     W2 + 8192, b2 + 128, x, n_nodes);

    k_poolhead<<<n_graphs, 256, 0, stream>>>(x, gstart, Ws_, bs_, Wbg1, bbg1, Wbg2, bbg2,
                                             Weh1, beh1, Weh2, beh2, out, n_graphs);
}

// Round 11
// 499.384 us; speedup vs baseline: 1.0873x; 1.0873x over previous
//
#include <hip/hip_runtime.h>
#include <hip/hip_fp16.h>
#include <cstddef>

// ---------------------------------------------------------------------------
// CrystalGNN (SchNet-style). R11: R9 skeleton + addressing-lean conv.
//   memset deg
//   k_pre     : hist deg[dst]++  +  gstart  +  x=emb[ids]  +  hA=x@W1_0+b1_0
//   scan a/b/c -> off[N+1], cursor[N]
//   k_scatter : dst-sorted AoS payload int4{src<<7 (BYTE offset into fp16 h),
//               A, B, 0}, A=exp(-1.125 d^2), B=exp(1.5 d); RBF_r=A*B^r*C_r
//               (C_r folded into filter weights) -> conv loop exp-free
//   per layer : k_conv — wave/edge, 8 gathers in flight, pointer-increment
//               payload loads, per-lane h base (2 VALU/gather addr),
//               CONSECUTIVE node chunk per wave, persistent single-batch grid
//               (1536 blk × 4 waves = 6144 = 6 waves/SIMD resident).
//               then k_gemm (h_next = x@W1'+b1')
//   k_poolhead: per-graph mean + two 2-layer MLP heads
// ---------------------------------------------------------------------------

// C_r = exp(-0.5 r^2), r = 0..9
#define RBF_C0 1.0f
#define RBF_C1 0.60653065971f
#define RBF_C2 0.13533528324f
#define RBF_C3 0.011108996538f
#define RBF_C4 3.3546262790e-4f
#define RBF_C5 3.7266531720e-6f
#define RBF_C6 1.5229979745e-8f
#define RBF_C7 2.2897348457e-11f
#define RBF_C8 1.2664165549e-14f
#define RBF_C9 2.5767043600e-18f

__device__ __forceinline__ float softplusf(float v) {
    return fmaxf(v, 0.0f) + log1pf(__expf(-fabsf(v)));
}

__device__ __forceinline__ float row_gemv(const float4* __restrict__ xr,
                                          const float w[64], float bj) {
    float a0 = bj, a1 = 0.f, a2 = 0.f, a3 = 0.f;
#pragma unroll
    for (int q = 0; q < 4; ++q) {
        float4 v0 = xr[4 * q + 0], v1 = xr[4 * q + 1];
        float4 v2 = xr[4 * q + 2], v3 = xr[4 * q + 3];
        a0 = fmaf(v0.x, w[16 * q + 0], a0);  a0 = fmaf(v0.y, w[16 * q + 1], a0);
        a0 = fmaf(v0.z, w[16 * q + 2], a0);  a0 = fmaf(v0.w, w[16 * q + 3], a0);
        a1 = fmaf(v1.x, w[16 * q + 4], a1);  a1 = fmaf(v1.y, w[16 * q + 5], a1);
        a1 = fmaf(v1.z, w[16 * q + 6], a1);  a1 = fmaf(v1.w, w[16 * q + 7], a1);
        a2 = fmaf(v2.x, w[16 * q + 8], a2);  a2 = fmaf(v2.y, w[16 * q + 9], a2);
        a2 = fmaf(v2.z, w[16 * q + 10], a2); a2 = fmaf(v2.w, w[16 * q + 11], a2);
        a3 = fmaf(v3.x, w[16 * q + 12], a3); a3 = fmaf(v3.y, w[16 * q + 13], a3);
        a3 = fmaf(v3.z, w[16 * q + 14], a3); a3 = fmaf(v3.w, w[16 * q + 15], a3);
    }
    return (a0 + a1) + (a2 + a3);
}

__device__ __forceinline__ float filt_ab(const float wp[10], float bj, float A, float B) {
    float P = wp[9];
    P = fmaf(B, P, wp[8]); P = fmaf(B, P, wp[7]); P = fmaf(B, P, wp[6]);
    P = fmaf(B, P, wp[5]); P = fmaf(B, P, wp[4]); P = fmaf(B, P, wp[3]);
    P = fmaf(B, P, wp[2]); P = fmaf(B, P, wp[1]); P = fmaf(B, P, wp[0]);
    return fmaf(A, P, bj);
}

// ---------------- hist + gstart + embed + gemm0 ----------------
__global__ void k_pre(const int* __restrict__ dst, int* __restrict__ deg,
                      const int* __restrict__ batch, int* __restrict__ gstart,
                      const int* __restrict__ ids, const float* __restrict__ emb,
                      const float* __restrict__ W1, const float* __restrict__ b1,
                      float* __restrict__ x, __half* __restrict__ hA,
                      int n_edges, int n_nodes, int n_graphs) {
    int tid = blockIdx.x * blockDim.x + threadIdx.x;
    int nth = gridDim.x * blockDim.x;
    for (int e = tid; e < n_edges; e += nth) atomicAdd(&deg[dst[e]], 1);
    for (int n = tid; n < n_nodes; n += nth) {
        int b = batch[n];
        int prev = (n == 0) ? -1 : batch[n - 1];
        for (int g = prev + 1; g <= b; ++g) gstart[g] = n;
        if (n == n_nodes - 1)
            for (int g = b + 1; g <= n_graphs; ++g) gstart[g] = n_nodes;
    }
    int lane = threadIdx.x & 63;
    int gw = __builtin_amdgcn_readfirstlane(tid >> 6);
    int nw = nth >> 6;
    float w[64];
#pragma unroll
    for (int k = 0; k < 64; ++k) w[k] = W1[k * 64 + lane];
    float bj = b1[lane];
    for (int n = gw; n < n_nodes; n += nw) {
        int id = __builtin_amdgcn_readfirstlane(ids[n]);
        const float4* xr = (const float4*)(emb + id * 64);
        float v = row_gemv(xr, w, bj);
        x[n * 64 + lane] = emb[id * 64 + lane];
        hA[n * 64 + lane] = __float2half(v);
    }
}

// ---------------- scan ----------------
__global__ void k_scana(const int* __restrict__ deg, int* __restrict__ off_,
                        int* __restrict__ bsum, int n) {
    __shared__ int s[256];
    int i = blockIdx.x * 256 + threadIdx.x;
    int v = (i < n) ? deg[i] : 0;
    s[threadIdx.x] = v;
    __syncthreads();
    for (int off = 1; off < 256; off <<= 1) {
        int t = (threadIdx.x >= off) ? s[threadIdx.x - off] : 0;
        __syncthreads();
        s[threadIdx.x] += t;
        __syncthreads();
    }
    if (i < n) off_[i + 1] = s[threadIdx.x];
    if (threadIdx.x == 255) bsum[blockIdx.x] = s[255];
}

__global__ void k_scanb(int* __restrict__ bsum, int nb) {
    __shared__ int s[256];
    int v = ((int)threadIdx.x < nb) ? bsum[threadIdx.x] : 0;
    s[threadIdx.x] = v;
    __syncthreads();
    for (int off = 1; off < 256; off <<= 1) {
        int t = (threadIdx.x >= off) ? s[threadIdx.x - off] : 0;
        __syncthreads();
        s[threadIdx.x] += t;
        __syncthreads();
    }
    if ((int)threadIdx.x < nb) bsum[threadIdx.x] = s[threadIdx.x] - v;  // exclusive
}

__global__ void k_scanc(const int* __restrict__ deg, const int* __restrict__ bsum,
                        int* __restrict__ off_, int* __restrict__ cursor, int n) {
    int i = blockIdx.x * blockDim.x + threadIdx.x;
    if (i < n) {
        int incl = off_[i + 1] + bsum[i >> 8];
        off_[i + 1] = incl;
        cursor[i] = incl - deg[i];
    }
    if (i == 0) off_[0] = 0;
}

// ---------------- scatter: payload {src<<7 byte-offset, A, B, 0} -----------
__global__ void k_scatter(const int* __restrict__ src, const int* __restrict__ dst,
                          const float* __restrict__ dist, int* __restrict__ cursor,
                          int4* __restrict__ psort, int n_edges) {
    int e = blockIdx.x * blockDim.x + threadIdx.x;
    if (e >= n_edges) return;
    int t = dst[e];
    int pos = atomicAdd(&cursor[t], 1);
    float d = dist[e];
    float A = __expf(-1.125f * d * d);
    float B = __expf(1.5f * d);
    psort[pos] = make_int4(src[e] << 7, __float_as_int(A), __float_as_int(B), 0);
}

// ---------------- gemm: h = x@W1_l + b1_l ----------------
__global__ __launch_bounds__(256, 4) void k_gemm(
        const float* __restrict__ X, const float* __restrict__ W,
        const float* __restrict__ bias, __half* __restrict__ Y, int n_nodes) {
    int lane = threadIdx.x & 63;
    int gw = __builtin_amdgcn_readfirstlane((blockIdx.x * blockDim.x + threadIdx.x) >> 6);
    int nw = (gridDim.x * blockDim.x) >> 6;
    float w[64];
#pragma unroll
    for (int k = 0; k < 64; ++k) w[k] = W[k * 64 + lane];
    float bj = bias[lane];
    for (int n = gw; n < n_nodes; n += nw) {
        const float4* xr = (const float4*)(X + n * 64);
        Y[n * 64 + lane] = __float2half(row_gemv(xr, w, bj));
    }
}

// ---------------- conv ----------------
// Wave processes a CONSECUTIVE chunk of nodes (psort streams sequentially).
// 8 gathers in flight; payload via incremented pointer (imm offsets 0..112);
// gather address = per-lane byte base + payload byte-offset (2 VALU).
__global__ __launch_bounds__(256, 6) void k_conv(
        const int4* __restrict__ ps, const int* __restrict__ off,
        const __half* __restrict__ h,
        const float* __restrict__ We, const float* __restrict__ be,
        const float* __restrict__ W2, const float* __restrict__ b2,
        float* __restrict__ x, int n_nodes, int chunk) {
    int lane = threadIdx.x & 63;
    int wv = (blockIdx.x * blockDim.x + threadIdx.x) >> 6;
    int n0 = __builtin_amdgcn_readfirstlane(wv * chunk);
    if (n0 >= n_nodes) return;
    int n1 = n0 + chunk;
    if (n1 > n_nodes) n1 = n_nodes;

    const float C[10] = {RBF_C0, RBF_C1, RBF_C2, RBF_C3, RBF_C4,
                         RBF_C5, RBF_C6, RBF_C7, RBF_C8, RBF_C9};
    float wp[10];
#pragma unroll
    for (int r = 0; r < 10; ++r) wp[r] = We[r * 64 + lane] * C[r];
    float bj  = be[lane];
    float b2j = b2[lane];
    const char* hb = (const char*)h + lane * 2;   // per-lane byte base

    int k1s = __builtin_amdgcn_readfirstlane(off[n0]);
    for (int n = n0; n < n1; ++n) {
        int k0 = k1s;
        k1s = __builtin_amdgcn_readfirstlane(off[n + 1]);
        int m = k1s - k0;
        const int4* pp = ps + k0;
        float acc = 0.0f;
        int k = 0;
        for (; k + 8 <= m; k += 8) {   // 8 gathers in flight
            int4 p0 = pp[0], p1 = pp[1], p2 = pp[2], p3 = pp[3];
            int4 p4 = pp[4], p5 = pp[5], p6 = pp[6], p7 = pp[7];
            pp += 8;
            float g0 = __half2float(*(const __half*)(hb + p0.x));
            float g1 = __half2float(*(const __half*)(hb + p1.x));
            float g2 = __half2float(*(const __half*)(hb + p2.x));
            float g3 = __half2float(*(const __half*)(hb + p3.x));
            float g4 = __half2float(*(const __half*)(hb + p4.x));
            float g5 = __half2float(*(const __half*)(hb + p5.x));
            float g6 = __half2float(*(const __half*)(hb + p6.x));
            float g7 = __half2float(*(const __half*)(hb + p7.x));
            acc = fmaf(g0, filt_ab(wp, bj, __int_as_float(p0.y), __int_as_float(p0.z)), acc);
            acc = fmaf(g1, filt_ab(wp, bj, __int_as_float(p1.y), __int_as_float(p1.z)), acc);
            acc = fmaf(g2, filt_ab(wp, bj, __int_as_float(p2.y), __int_as_float(p2.z)), acc);
            acc = fmaf(g3, filt_ab(wp, bj, __int_as_float(p3.y), __int_as_float(p3.z)), acc);
            acc = fmaf(g4, filt_ab(wp, bj, __int_as_float(p4.y), __int_as_float(p4.z)), acc);
            acc = fmaf(g5, filt_ab(wp, bj, __int_as_float(p5.y), __int_as_float(p5.z)), acc);
            acc = fmaf(g6, filt_ab(wp, bj, __int_as_float(p6.y), __int_as_float(p6.z)), acc);
            acc = fmaf(g7, filt_ab(wp, bj, __int_as_float(p7.y), __int_as_float(p7.z)), acc);
        }
        for (; k + 4 <= m; k += 4) {
            int4 p0 = pp[0], p1 = pp[1], p2 = pp[2], p3 = pp[3];
            pp += 4;
            float g0 = __half2float(*(const __half*)(hb + p0.x));
            float g1 = __half2float(*(const __half*)(hb + p1.x));
            float g2 = __half2float(*(const __half*)(hb + p2.x));
            float g3 = __half2float(*(const __half*)(hb + p3.x));
            acc = fmaf(g0, filt_ab(wp, bj, __int_as_float(p0.y), __int_as_float(p0.z)), acc);
            acc = fmaf(g1, filt_ab(wp, bj, __int_as_float(p1.y), __int_as_float(p1.z)), acc);
            acc = fmaf(g2, filt_ab(wp, bj, __int_as_float(p2.y), __int_as_float(p2.z)), acc);
            acc = fmaf(g3, filt_ab(wp, bj, __int_as_float(p3.y), __int_as_float(p3.z)), acc);
        }
        for (; k < m; ++k) {
            int4 p = pp[0];
            pp += 1;
            float g = __half2float(*(const __half*)(hb + p.x));
            acc = fmaf(g, filt_ab(wp, bj, __int_as_float(p.y), __int_as_float(p.z)), acc);
        }
        // x_new = softplus(x + b2 + acc @ W2)
        float o0 = b2j + x[n * 64 + lane];
        float o1 = 0.f, o2 = 0.f, o3 = 0.f;
#pragma unroll 4
        for (int kk = 0; kk < 16; ++kk) {
            o0 = fmaf(__shfl(acc, kk),      W2[(kk)      * 64 + lane], o0);
            o1 = fmaf(__shfl(acc, kk + 16), W2[(kk + 16) * 64 + lane], o1);
            o2 = fmaf(__shfl(acc, kk + 32), W2[(kk + 32) * 64 + lane], o2);
            o3 = fmaf(__shfl(acc, kk + 48), W2[(kk + 48) * 64 + lane], o3);
        }
        x[n * 64 + lane] = softplusf((o0 + o1) + (o2 + o3));
    }
}

// ---------------- fused pool + head: one block per graph ----------------
__global__ void k_poolhead(const float* __restrict__ x, const int* __restrict__ gstart,
                           const float* __restrict__ Ws, const float* __restrict__ bs,
                           const float* __restrict__ Wbg1, const float* __restrict__ bbg1,
                           const float* __restrict__ Wbg2, const float* __restrict__ bbg2,
                           const float* __restrict__ Weh1, const float* __restrict__ beh1,
                           const float* __restrict__ Weh2, const float* __restrict__ beh2,
                           float* __restrict__ out, int n_graphs) {
    __shared__ float red[256];
    __shared__ float c[64];
    __shared__ float h1[128];
    int g = blockIdx.x;
    int t = threadIdx.x, j = t & 63, part = t >> 6;
    int s0 = gstart[g], s1 = gstart[g + 1];
    float acc = 0.0f;
    for (int n = s0 + part; n < s1; n += 4) acc += x[n * 64 + j];
    red[t] = acc;
    __syncthreads();
    if (part == 0)
        c[j] = (red[j] + red[64 + j] + red[128 + j] + red[192 + j]) /
               fmaxf((float)(s1 - s0), 1.0f);
    __syncthreads();
    if (t < 128) {
        float av = bs[t];
#pragma unroll 8
        for (int k = 0; k < 64; ++k) av = fmaf(c[k], Ws[k * 128 + t], av);
        h1[t] = fmaxf(av, 0.0f);
    }
    __syncthreads();
    if (t < 128) {
        const float* W1p = (t < 64) ? Wbg1 : Weh1;
        const float* b1p = (t < 64) ? bbg1 : beh1;
        const float* W2p = (t < 64) ? Wbg2 : Weh2;
        float b2v = (t < 64) ? bbg2[0] : beh2[0];
        int ln = t & 63;
        float a2 = b1p[ln];
#pragma unroll 8
        for (int k = 0; k < 128; ++k) a2 = fmaf(h1[k], W1p[k * 64 + ln], a2);
        a2 = fmaxf(a2, 0.0f);
        float pr = a2 * W2p[ln];
#pragma unroll
        for (int off = 32; off > 0; off >>= 1) pr += __shfl_down(pr, off);
        if (ln == 0) out[(t < 64 ? 0 : n_graphs) + g] = pr + b2v;
    }
}

extern "C" void kernel_launch(void* const* d_in, const int* in_sizes, int n_in,
                              void* d_out, int out_size, void* d_ws, size_t ws_size,
                              hipStream_t stream) {
    const int*   x_ids = (const int*)d_in[0];
    const int*   eidx  = (const int*)d_in[1];
    const float* eattr = (const float*)d_in[2];
    const int*   batch = (const int*)d_in[3];
    const float* emb   = (const float*)d_in[4];
    const float* W1    = (const float*)d_in[5];
    const float* b1    = (const float*)d_in[6];
    const float* We    = (const float*)d_in[7];
    const float* be    = (const float*)d_in[8];
    const float* W2    = (const float*)d_in[9];
    const float* b2    = (const float*)d_in[10];
    const float* Ws_   = (const float*)d_in[11];
    const float* bs_   = (const float*)d_in[12];
    const float* Wbg1  = (const float*)d_in[13];
    const float* bbg1  = (const float*)d_in[14];
    const float* Wbg2  = (const float*)d_in[15];
    const float* bbg2  = (const float*)d_in[16];
    const float* Weh1  = (const float*)d_in[17];
    const float* beh1  = (const float*)d_in[18];
    const float* Weh2  = (const float*)d_in[19];
    const float* beh2  = (const float*)d_in[20];

    int n_nodes  = in_sizes[0];
    int n_edges  = in_sizes[2];
    int n_graphs = out_size / 2;
    const int* src = eidx;
    const int* dst = eidx + n_edges;

    char* p = (char*)d_ws;
    float* x     = (float*)p;   p += (size_t)n_nodes * 64 * sizeof(float);
    __half* hA   = (__half*)p;  p += (size_t)n_nodes * 64 * sizeof(__half);
    __half* hB   = (__half*)p;  p += (size_t)n_nodes * 64 * sizeof(__half);
    int4* psort  = (int4*)p;    p += (size_t)n_edges * sizeof(int4);
    int* deg     = (int*)p;     p += (size_t)n_nodes * sizeof(int);
    int* off_    = (int*)p;     p += (size_t)(n_nodes + 1) * sizeof(int);
    int* cursor  = (int*)p;     p += (size_t)n_nodes * sizeof(int);
    int* bsum    = (int*)p;     p += 256 * sizeof(int);
    int* gstart  = (int*)p;     p += (size_t)(n_graphs + 1) * sizeof(int);
    float* out   = (float*)d_out;

    int nchunks = (n_nodes + 255) / 256;
    int nbE = (n_edges + 255) / 256;
    int nbN = (n_nodes + 255) / 256;

    // conv grid: 1536 blocks x 4 waves = 6144 waves, single resident batch
    // (launch_bounds(256,6) -> 6 blocks/CU x 256 CUs). chunk = consecutive
    // nodes per wave.
    const int conv_blocks = 1536;
    int conv_waves = conv_blocks * 4;
    int chunk = (n_nodes + conv_waves - 1) / conv_waves;

    hipMemsetAsync(deg, 0, (size_t)n_nodes * sizeof(int), stream);
    k_pre<<<nbE, 256, 0, stream>>>(dst, deg, batch, gstart, x_ids, emb, W1, b1,
                                   x, hA, n_edges, n_nodes, n_graphs);
    k_scana<<<nchunks, 256, 0, stream>>>(deg, off_, bsum, n_nodes);
    k_scanb<<<1, 256, 0, stream>>>(bsum, nchunks);
    k_scanc<<<nbN, 256, 0, stream>>>(deg, bsum, off_, cursor, n_nodes);
    k_scatter<<<nbE, 256, 0, stream>>>(src, dst, eattr, cursor, psort, n_edges);

    k_conv<<<conv_blocks, 256, 0, stream>>>(psort, off_, hA, We, be, W2, b2,
                                            x, n_nodes, chunk);
    k_gemm<<<1024, 256, 0, stream>>>(x, W1 + 4096, b1 + 64, hB, n_nodes);
    k_conv<<<conv_blocks, 256, 0, stream>>>(psort, off_, hB, We + 640, be + 64,
                                            W2 + 4096, b2 + 64, x, n_nodes, chunk);
    k_gemm<<<1024, 256, 0, stream>>>(x, W1 + 8192, b1 + 128, hA, n_nodes);
    k_conv<<<conv_blocks, 256, 0, stream>>>(psort, off_, hA, We + 1280, be + 128,
                                            W2 + 8192, b2 + 128, x, n_nodes, chunk);

    k_poolhead<<<n_graphs, 256, 0, stream>>>(x, gstart, Ws_, bs_, Wbg1, bbg1, Wbg2, bbg2,
                                             Weh1, beh1, Weh2, beh2, out, n_graphs);
}